// Round 17
// baseline (603.043 us; speedup 1.0000x reference)
//
#include <hip/hip_runtime.h>
#include <math.h>

typedef __bf16 bf16;
typedef __attribute__((ext_vector_type(8))) __bf16 bf16x8;
typedef __attribute__((ext_vector_type(4))) float f32x4;
typedef __attribute__((ext_vector_type(4))) short s16x4;

#define T_HASH (1u << 19)
#define PRIME1 2654435761u
#define PRIME2 805459861u
#define FP8_SCALE 8192.0f
#define FP8_INV   (1.0f / 8192.0f)

struct Levels { unsigned R[16]; unsigned mY[16]; unsigned mZ[16]; unsigned df[16]; };

__device__ __forceinline__ unsigned umin_(unsigned a, unsigned b) { return a < b ? a : b; }

// swizzled LDS byte offset: rows are 512B (256 bf16), XOR row-bits into the 16B-slot bits
__device__ __forceinline__ int swzoff(int row, int colByte) {
    return row * 512 + (colByte ^ ((row & 7) << 4));
}

__device__ __forceinline__ void stb(char* base, int row, int col, float v) {
    *(bf16*)(base + swzoff(row, col * 2)) = (bf16)v;
}
__device__ __forceinline__ void stw(char* base, int row, int col, unsigned short v) {
    *(unsigned short*)(base + swzoff(row, col * 2)) = v;
}

// fast softplus(100v)/100: v_exp/v_log based; v>0.25 -> identity (tail < 2e-13)
__device__ __forceinline__ float softplus100f(float v) {
    float u = v * 144.2695041f;                       // 100 * log2(e)
    float e = __builtin_amdgcn_exp2f(u);
    float y = __builtin_amdgcn_logf(1.f + e) * 0.006931471806f;  // log2->ln, /100
    return v > 0.25f ? v : y;
}

__device__ __forceinline__ unsigned short f2bfu(float v) {
    bf16 h = (bf16)v;
    return *(unsigned short*)&h;
}

// ---------------- weight prep: W = g * v / ||v||_row, cast to bf16, pad ----------------
__global__ void prep_weights(const float* __restrict__ v0, const float* __restrict__ g0,
                             const float* __restrict__ v1, const float* __restrict__ g1,
                             const float* __restrict__ v2, const float* __restrict__ g2,
                             unsigned short* __restrict__ W0, unsigned short* __restrict__ W1,
                             unsigned short* __restrict__ W2) {
    int r = blockIdx.x;
    int lane = threadIdx.x;
    const float* src = nullptr; const float* g = nullptr; unsigned short* dst; int K, Kp, row;
    if (r < 256)      { row = r;       src = v0 + row * 71;  g = g0; dst = W0 + row * 96;  K = 71;  Kp = 96;  }
    else if (r < 512) { row = r - 256; src = v1 + row * 256; g = g1; dst = W1 + row * 256; K = 256; Kp = 256; }
    else              { row = r - 512; if (row < 257) { src = v2 + row * 256; g = g2; }
                        dst = W2 + row * 256; K = 256; Kp = 256; }
    float ss = 0.f;
    if (src) for (int c = lane; c < K; c += 64) { float v = src[c]; ss += v * v; }
    for (int off = 32; off; off >>= 1) ss += __shfl_down(ss, off);
    ss = __shfl(ss, 0);
    float scale = src ? (g[row] / sqrtf(ss)) : 0.f;
    for (int c = lane; c < Kp; c += 64) {
        float v = (src && c < K) ? src[c] * scale : 0.f;
        dst[c] = f2bfu(v);
    }
}

// ---------------- table conversion f32x2 -> packed fp8 e4m3 x2 (u16), scaled 2^13 ----
__global__ void conv_tables(const float2* __restrict__ t, unsigned short* __restrict__ tf8) {
    size_t i = (size_t)blockIdx.x * 256 + threadIdx.x;
    float2 e = t[i];
    int pk = __builtin_amdgcn_cvt_pk_fp8_f32(e.x * FP8_SCALE, e.y * FP8_SCALE, 0, false);
    tf8[i] = (unsigned short)(pk & 0xffff);
}

// ---------------- level-partitioned encode: HASHED levels only (5..15) ----------------
// blockIdx%8 -> XCD slot; round 0: level 5+slot, round 1: level 13+slot (slot<3).
// fp8 tables: 1-2MB per XCD resident in 4MB L2.
__global__ __launch_bounds__(256, 8)
void encode_levels(const float* __restrict__ x, const unsigned short* __restrict__ tf8,
                   unsigned* __restrict__ featsLM, Levels lv, int npts) {
    const int slot = blockIdx.x & 7, seq = blockIdx.x >> 3;
    const int round = seq & 1;
    if (round && slot >= 3) return;              // 11 hashed levels total
    const int l = round ? (13 + slot) : (5 + slot);
    const int group = seq >> 1;
    const unsigned Ru = lv.R[l], mY = lv.mY[l], mZ = lv.mZ[l];
    const bool dense = lv.df[l] != 0;
    const unsigned short* __restrict__ tl = tf8 + (size_t)l * T_HASH;
    unsigned* __restrict__ fout = featsLM + (size_t)(l - 5) * npts;
    const float Rf = (float)Ru;
    const int base = group * 1024 + threadIdx.x;
#pragma unroll
    for (int k = 0; k < 4; ++k) {
        const int p = base + k * 256;
        float xr0 = x[p * 3 + 0], xr1 = x[p * 3 + 1], xr2 = x[p * 3 + 2];
        const float cx = fminf(fmaxf(xr0, 0.f), 1.f);
        const float cy = fminf(fmaxf(xr1, 0.f), 1.f);
        const float cz = fminf(fmaxf(xr2, 0.f), 1.f);
        float px = cx * Rf, py = cy * Rf, pz = cz * Rf;
        float fx = floorf(px), fy = floorf(py), fz = floorf(pz);
        float wx = px - fx, wy = py - fy, wz = pz - fz;
        unsigned ix = (unsigned)fx, iy = (unsigned)fy, iz = (unsigned)fz;
        unsigned xc0 = ix, xc1 = umin_(ix + 1u, Ru);
        unsigned y0 = iy * mY, y1 = umin_(iy + 1u, Ru) * mY;
        unsigned z0 = iz * mZ, z1 = umin_(iz + 1u, Ru) * mZ;
        unsigned yzA[4] = { y0 + z0, y1 + z0, y0 + z1, y1 + z1 };
        float w0x = 1.f - wx, w0y = 1.f - wy, w0z = 1.f - wz;
        float wyz[4] = { w0y * w0z, wy * w0z, w0y * wz, wy * wz };
        float a0 = 0.f, a1 = 0.f;
#pragma unroll
        for (int c = 0; c < 8; ++c) {
            const int ox = c & 1, cyz = c >> 1;
            unsigned xc = ox ? xc1 : xc0;
            unsigned gi = dense ? (xc + yzA[cyz])
                                : ((xc ^ yzA[cyz]) & (T_HASH - 1u));
            unsigned u = (unsigned)tl[gi];
            float ex = __builtin_amdgcn_cvt_f32_fp8(u, 0);
            float ey = __builtin_amdgcn_cvt_f32_fp8(u, 1);
            float wc = (ox ? wx : w0x) * wyz[cyz];
            a0 = fmaf(wc, ex, a0);
            a1 = fmaf(wc, ey, a1);
        }
        a0 *= FP8_INV; a1 *= FP8_INV;
        unsigned outw = (unsigned)f2bfu(a0) | ((unsigned)f2bfu(a1) << 16);
        __builtin_nontemporal_store(outw, &fout[p]);
    }
}

// ---------------- fused MLP ----------------
// block = 64 points, 1024 threads (16 waves)  [R11/R13 structure — best measured]
// Wave w owns output cols [w*16,w*16+16) for ALL 64 points (4 point-sub-tiles).
// Per K-step: 1 W a-load (depth-2 prefetch, 3-slot rotation) + 4 LDS b-reads + 4 MFMA.
// Dense hash levels 0-4 gathered inline (tables ~700KB fp8, L2-hot everywhere).
// Col 256 via distributed VALU dot. Flat copy-out (1028 full aligned 64B lines).

#define STG_STRIDE 260   // floats; 1040B row, 16B-aligned

template<int KSTEPS, int ROWLEN>
__device__ __forceinline__ void layer_mid(const char* __restrict__ inbuf,
                                          const unsigned short* __restrict__ W,
                                          const float* __restrict__ bias,
                                          char* __restrict__ outbuf, int tid) {
    const int lane = tid & 63, wave = tid >> 6;
    const int lrow = lane & 15, lk = lane >> 4;
    const unsigned short* __restrict__ wrow = W + (wave * 16 + lrow) * ROWLEN + lk * 8;
    f32x4 acc[4] = {};
    bf16x8 abuf[3];
    abuf[0] = *(const bf16x8*)(wrow);
    if (KSTEPS > 1) abuf[1] = *(const bf16x8*)(wrow + 32);
#pragma unroll
    for (int ks = 0; ks < KSTEPS; ++ks) {
        if (ks + 2 < KSTEPS) abuf[(ks + 2) % 3] = *(const bf16x8*)(wrow + (ks + 2) * 32);
        const int k0 = ks * 32 + lk * 8;
        bf16x8 b[4];
#pragma unroll
        for (int pt = 0; pt < 4; ++pt)
            b[pt] = *(const bf16x8*)(inbuf + swzoff(pt * 16 + lrow, k0 * 2));
#pragma unroll
        for (int pt = 0; pt < 4; ++pt)
            acc[pt] = __builtin_amdgcn_mfma_f32_16x16x32_bf16(abuf[ks % 3], b[pt], acc[pt], 0, 0, 0);
    }
    const int c0 = wave * 16 + lk * 4;
    const float4 bv = *(const float4*)(bias + c0);
#pragma unroll
    for (int pt = 0; pt < 4; ++pt) {
        const int p = pt * 16 + lrow;
        s16x4 o;
        o.x = (short)f2bfu(softplus100f(acc[pt][0] + bv.x));
        o.y = (short)f2bfu(softplus100f(acc[pt][1] + bv.y));
        o.z = (short)f2bfu(softplus100f(acc[pt][2] + bv.z));
        o.w = (short)f2bfu(softplus100f(acc[pt][3] + bv.w));
        *(s16x4*)(outbuf + swzoff(p, c0 * 2)) = o;
    }
}

__device__ __forceinline__ void layer_fin(const char* __restrict__ inbuf,
                                          const unsigned short* __restrict__ W2,
                                          const float* __restrict__ b2,
                                          float* __restrict__ stg,
                                          float* __restrict__ out, int tid, int blk) {
    const int lane = tid & 63, wave = tid >> 6;
    const int lrow = lane & 15, lk = lane >> 4;
    const unsigned short* __restrict__ wrow = W2 + (wave * 16 + lrow) * 256 + lk * 8;
    f32x4 acc[4] = {};
    bf16x8 abuf[3];
    abuf[0] = *(const bf16x8*)(wrow);
    abuf[1] = *(const bf16x8*)(wrow + 32);
#pragma unroll
    for (int ks = 0; ks < 8; ++ks) {
        if (ks + 2 < 8) abuf[(ks + 2) % 3] = *(const bf16x8*)(wrow + (ks + 2) * 32);
        const int k0 = ks * 32 + lk * 8;
        bf16x8 b[4];
#pragma unroll
        for (int pt = 0; pt < 4; ++pt)
            b[pt] = *(const bf16x8*)(inbuf + swzoff(pt * 16 + lrow, k0 * 2));
#pragma unroll
        for (int pt = 0; pt < 4; ++pt)
            acc[pt] = __builtin_amdgcn_mfma_f32_16x16x32_bf16(abuf[ks % 3], b[pt], acc[pt], 0, 0, 0);
    }
    // ---- col 256: distributed VALU dot. p = tid>>4 (64 pts), sub = tid&15, 16 k each ----
    const int p = tid >> 4, sub = tid & 15;
    float part = 0.f;
    {
        const unsigned short* __restrict__ w2r = W2 + 256 * 256 + sub * 16;
        bf16x8 h0 = *(const bf16x8*)(inbuf + swzoff(p, sub * 32));
        bf16x8 h1 = *(const bf16x8*)(inbuf + swzoff(p, sub * 32 + 16));
        bf16x8 w0 = *(const bf16x8*)(w2r);
        bf16x8 w1 = *(const bf16x8*)(w2r + 8);
#pragma unroll
        for (int j = 0; j < 8; ++j) {
            part = fmaf((float)h0[j], (float)w0[j], part);
            part = fmaf((float)h1[j], (float)w1[j], part);
        }
    }
#pragma unroll
    for (int m = 1; m < 16; m <<= 1) part += __shfl_xor(part, m);

    __syncthreads();   // all reads of inbuf done; stg aliases the h-buffers
    const int c0 = wave * 16 + lk * 4;
    const float4 bv = *(const float4*)(b2 + c0);
#pragma unroll
    for (int pt = 0; pt < 4; ++pt) {
        const int pr = pt * 16 + lrow;
        f32x4 v;
        v[0] = acc[pt][0] + bv.x;
        v[1] = acc[pt][1] + bv.y;
        v[2] = acc[pt][2] + bv.z;
        v[3] = acc[pt][3] + bv.w;
        *(f32x4*)(stg + pr * STG_STRIDE + c0) = v;   // 16B-aligned
    }
    if (sub == 0) stg[p * STG_STRIDE + 256] = part + b2[256];
    __syncthreads();
    // ---- flat copy-out: block span = 16448 floats = 1028 full 64B lines, aligned ----
    float* __restrict__ dst = out + (size_t)blk * 16448;
#pragma unroll
    for (int r = 0; r < 4; ++r) {
        const int f0 = (r * 1024 + tid) * 4;
        const unsigned pp = ((unsigned)f0 * 65281u) >> 24;        // f0 / 257
        const int cc = f0 - (int)pp * 257;
        f32x4 v;
#pragma unroll
        for (int u = 0; u < 4; ++u) {
            int c2 = cc + u; unsigned p2 = pp;
            if (c2 >= 257) { c2 -= 257; p2++; }
            v[u] = stg[p2 * STG_STRIDE + c2];
        }
        *(f32x4*)(dst + f0) = v;                 // plain 16B store; L2 assembles lines
    }
    if (tid < 64) {
        const int f0 = 16384 + tid;
        const unsigned pp = ((unsigned)f0 * 65281u) >> 24;
        const int cc = f0 - (int)pp * 257;
        dst[f0] = stg[pp * STG_STRIDE + cc];
    }
}

template<bool SPLIT>
__global__ __launch_bounds__(1024, 8)
void fused_net(const float* __restrict__ x, const float2* __restrict__ tables,
               const unsigned short* __restrict__ tf8,
               const unsigned* __restrict__ featsLM,
               const unsigned short* __restrict__ W0, const unsigned short* __restrict__ W1,
               const unsigned short* __restrict__ W2,
               const float* __restrict__ b0, const float* __restrict__ b1, const float* __restrict__ b2,
               float* __restrict__ out, Levels lv, int npts) {
    __shared__ __align__(16) char smem[66560 + 256];   // h-buffers; stg aliases (64*260*4=66560)
    unsigned* sR  = (unsigned*)(smem + 66560);
    unsigned* sMY = sR + 16;
    unsigned* sMZ = sR + 32;
    unsigned* sDF = sR + 48;
    char* buf0 = smem;            // h0, later h2
    char* buf1 = smem + 32768;    // h1
    float* stg = (float*)smem;    // fp32 staging for final output (aliases h-buffers)
    const int tid = threadIdx.x;
    const int blk = blockIdx.x;

    if (tid >= 960) {
        int i = tid - 960;
        if (i < 16)      sR[i]  = lv.R[i];
        else if (i < 32) sMY[i - 16] = lv.mY[i - 16];
        else if (i < 48) sMZ[i - 32] = lv.mZ[i - 32];
        else             sDF[i - 48] = lv.df[i - 48];
    }
    __syncthreads();

    const int p = tid >> 4, sub = tid & 15;
    const float xr0 = x[(size_t)blk * 192 + p * 3 + 0];
    const float xr1 = x[(size_t)blk * 192 + p * 3 + 1];
    const float xr2 = x[(size_t)blk * 192 + p * 3 + 2];

    if (SPLIT) {
        // coalesced feats load: hashed levels 0..10 (actual levels 5..15)
        // wave reads 64 consecutive u32 of one level = 256B contiguous.
        const int l = tid >> 6, pt = tid & 63;
        if (l < 11) {
            unsigned u = featsLM[(size_t)l * npts + blk * 64 + pt];
            stw(buf0, pt, 49 + 2 * l, (unsigned short)(u & 0xffffu));
            stw(buf0, pt, 50 + 2 * l, (unsigned short)(u >> 16));
        }
    }

    // ---- positional embedding: 3 cols per sub-thread (subs 0..12) ----
    if (sub < 13) {
        int c0 = sub * 3;
#pragma unroll
        for (int u = 0; u < 3; ++u) {
            int c = c0 + u;
            if (c >= 39) break;
            float v;
            if (c < 3) v = (c == 0) ? xr0 : (c == 1 ? xr1 : xr2);
            else {
                int q = c - 3, j = q / 6, k = q - j * 6;
                int axis = (k < 3) ? k : k - 3;
                float xv = axis == 0 ? xr0 : (axis == 1 ? xr1 : xr2);
                float fx = (float)(1 << j) * xv;
                v = (k < 3) ? __sinf(fx) : __cosf(fx);
            }
            stb(buf0, p, c, v);
        }
    }
    for (int c = 71 + sub; c < 96; c += 16) stb(buf0, p, c, 0.f);

    if (SPLIT) {
        // ---- dense levels 0..4 inline: sub<5 gathers its level from fp8 tables ----
        if (sub < 5) {
            const int l = sub;
            const float cx = fminf(fmaxf(xr0, 0.f), 1.f);
            const float cy = fminf(fmaxf(xr1, 0.f), 1.f);
            const float cz = fminf(fmaxf(xr2, 0.f), 1.f);
            const unsigned Ru = sR[l], mY = sMY[l], mZ = sMZ[l];
            const unsigned short* __restrict__ tl = tf8 + (size_t)l * T_HASH;
            const float Rf = (float)Ru;
            float px = cx * Rf, py = cy * Rf, pz = cz * Rf;
            float fx = floorf(px), fy = floorf(py), fz = floorf(pz);
            float wx = px - fx, wy = py - fy, wz = pz - fz;
            unsigned ix = (unsigned)fx, iy = (unsigned)fy, iz = (unsigned)fz;
            unsigned xc0 = ix, xc1 = umin_(ix + 1u, Ru);
            unsigned y0 = iy * mY, y1 = umin_(iy + 1u, Ru) * mY;
            unsigned z0 = iz * mZ, z1 = umin_(iz + 1u, Ru) * mZ;
            unsigned yzA[4] = { y0 + z0, y1 + z0, y0 + z1, y1 + z1 };
            float w0x = 1.f - wx, w0y = 1.f - wy, w0z = 1.f - wz;
            float wyz[4] = { w0y * w0z, wy * w0z, w0y * wz, wy * wz };
            float a0 = 0.f, a1 = 0.f;
#pragma unroll
            for (int c = 0; c < 8; ++c) {
                const int ox = c & 1, cyz = c >> 1;
                unsigned xc = ox ? xc1 : xc0;
                unsigned gi = xc + yzA[cyz];            // dense by construction
                unsigned u = (unsigned)tl[gi];
                float ex = __builtin_amdgcn_cvt_f32_fp8(u, 0);
                float ey = __builtin_amdgcn_cvt_f32_fp8(u, 1);
                float wc = (ox ? wx : w0x) * wyz[cyz];
                a0 = fmaf(wc, ex, a0);
                a1 = fmaf(wc, ey, a1);
            }
            stb(buf0, p, 39 + 2 * l, a0 * FP8_INV);
            stb(buf0, p, 40 + 2 * l, a1 * FP8_INV);
        }
    } else {
        // fallback: inline hash gather (1 level per sub-thread), fp32 tables
        const int l = sub;
        const float cx = fminf(fmaxf(xr0, 0.f), 1.f);
        const float cy = fminf(fmaxf(xr1, 0.f), 1.f);
        const float cz = fminf(fmaxf(xr2, 0.f), 1.f);
        const unsigned Ru = sR[l], mY = sMY[l], mZ = sMZ[l];
        const bool dense = sDF[l] != 0;
        const unsigned lofs = (unsigned)l << 19;
        const float Rf = (float)Ru;
        float px = cx * Rf, py = cy * Rf, pz = cz * Rf;
        float fx = floorf(px), fy = floorf(py), fz = floorf(pz);
        float wx = px - fx, wy = py - fy, wz = pz - fz;
        unsigned ix = (unsigned)fx, iy = (unsigned)fy, iz = (unsigned)fz;
        unsigned xc0 = ix, xc1 = umin_(ix + 1u, Ru);
        unsigned y0 = iy * mY, y1 = umin_(iy + 1u, Ru) * mY;
        unsigned z0 = iz * mZ, z1 = umin_(iz + 1u, Ru) * mZ;
        unsigned yzA[4] = { y0 + z0 + lofs, y1 + z0 + lofs, y0 + z1 + lofs, y1 + z1 + lofs };
        unsigned yzX[4] = { y0 ^ z0, y1 ^ z0, y0 ^ z1, y1 ^ z1 };
        float w0x = 1.f - wx, w0y = 1.f - wy, w0z = 1.f - wz;
        float wyz[4] = { w0y * w0z, wy * w0z, w0y * wz, wy * wz };
        float a0 = 0.f, a1 = 0.f;
#pragma unroll
        for (int c = 0; c < 8; ++c) {
            const int ox = c & 1, cyz = c >> 1;
            unsigned xc = ox ? xc1 : xc0;
            unsigned fd = xc + yzA[cyz];
            unsigned fh = ((xc ^ yzX[cyz]) & (T_HASH - 1u)) + lofs;
            unsigned gi = dense ? fd : fh;
            float2 e2 = tables[gi];
            float wc = (ox ? wx : w0x) * wyz[cyz];
            a0 = fmaf(wc, e2.x, a0);
            a1 = fmaf(wc, e2.y, a1);
        }
        stb(buf0, p, 39 + 2 * l, a0);
        stb(buf0, p, 40 + 2 * l, a1);
    }
    __syncthreads();

    layer_mid<3, 96>(buf0, W0, b0, buf1, tid);    // 71(->96) -> 256
    __syncthreads();
    layer_mid<8, 256>(buf1, W1, b1, buf0, tid);   // 256 -> 256
    __syncthreads();
    layer_fin(buf0, W2, b2, stg, out, tid, blk);  // 256 -> 257, flat coalesced out
}

extern "C" void kernel_launch(void* const* d_in, const int* in_sizes, int n_in,
                              void* d_out, int out_size, void* d_ws, size_t ws_size,
                              hipStream_t stream) {
    const float*  x      = (const float*)d_in[0];
    const float2* tables = (const float2*)d_in[1];
    const float*  v0 = (const float*)d_in[2];
    const float*  g0 = (const float*)d_in[3];
    const float*  b0 = (const float*)d_in[4];
    const float*  v1 = (const float*)d_in[5];
    const float*  g1 = (const float*)d_in[6];
    const float*  b1 = (const float*)d_in[7];
    const float*  v2 = (const float*)d_in[8];
    const float*  g2 = (const float*)d_in[9];
    const float*  b2 = (const float*)d_in[10];

    unsigned short* W0 = (unsigned short*)d_ws;          // [256][96]
    unsigned short* W1 = W0 + 256 * 96;                  // [256][256]
    unsigned short* W2 = W1 + 256 * 256;                 // [272][256]
    size_t ofs_tf8   = 319488;                           // fp8 tables: 16 levels x 512K x 2B = 16MB
    size_t ofs_feats = ofs_tf8 + (size_t)16 * T_HASH * 2;
    size_t need      = ofs_feats + (size_t)16 * T_HASH * 4;
    unsigned short* tf8 = (unsigned short*)((char*)d_ws + ofs_tf8);
    unsigned* featsLM   = (unsigned*)((char*)d_ws + ofs_feats);
    bool use_split = ws_size >= need;

    Levels lv;
    double SCALE = pow(2.0, log2(2048.0 / 16.0) / 15.0);
    for (int l = 0; l < 16; ++l) {
        double r = 16.0 * pow(SCALE, (double)l);
        unsigned R = (unsigned)ceil(r);
        lv.R[l] = R;
        unsigned long long s = (unsigned long long)R + 1;
        int dense = (s * s * s <= (unsigned long long)T_HASH) ? 1 : 0;
        lv.df[l] = dense;
        lv.mY[l] = dense ? (R + 1u) : PRIME1;
        lv.mZ[l] = dense ? (R + 1u) * (R + 1u) : PRIME2;
    }

    prep_weights<<<784, 64, 0, stream>>>(v0, g0, v1, g1, v2, g2, W0, W1, W2);

    int n = in_sizes[0] / 3;          // 524288
    int nblk = n / 64;                // 8192

    if (use_split) {
        conv_tables<<<16 * T_HASH / 256, 256, 0, stream>>>(tables, tf8);
        encode_levels<<<8 * (n / 1024) * 2, 256, 0, stream>>>(x, tf8, featsLM, lv, n);
        fused_net<true><<<nblk, 1024, 0, stream>>>(x, tables, tf8, featsLM, W0, W1, W2,
                                                   b0, b1, b2, (float*)d_out, lv, n);
    } else {
        fused_net<false><<<nblk, 1024, 0, stream>>>(x, tables, tf8, nullptr, W0, W1, W2,
                                                    b0, b1, b2, (float*)d_out, lv, n);
    }
}

// Round 18
// 578.857 us; speedup vs baseline: 1.0418x; 1.0418x over previous
//
#include <hip/hip_runtime.h>
#include <math.h>

typedef __bf16 bf16;
typedef __attribute__((ext_vector_type(8))) __bf16 bf16x8;
typedef __attribute__((ext_vector_type(4))) float f32x4;
typedef __attribute__((ext_vector_type(4))) short s16x4;

#define T_HASH (1u << 19)
#define PRIME1 2654435761u
#define PRIME2 805459861u
#define FP8_SCALE 8192.0f
#define FP8_INV   (1.0f / 8192.0f)

struct Levels { unsigned R[16]; unsigned mY[16]; unsigned mZ[16]; unsigned df[16]; };

__device__ __forceinline__ unsigned umin_(unsigned a, unsigned b) { return a < b ? a : b; }

// swizzled LDS byte offset: rows are 512B (256 bf16), XOR row-bits into the 16B-slot bits
__device__ __forceinline__ int swzoff(int row, int colByte) {
    return row * 512 + (colByte ^ ((row & 7) << 4));
}

__device__ __forceinline__ void stb(char* base, int row, int col, float v) {
    *(bf16*)(base + swzoff(row, col * 2)) = (bf16)v;
}
__device__ __forceinline__ void stw(char* base, int row, int col, unsigned short v) {
    *(unsigned short*)(base + swzoff(row, col * 2)) = v;
}

// fast softplus(100v)/100: v_exp/v_log based; v>0.25 -> identity (tail < 2e-13)
__device__ __forceinline__ float softplus100f(float v) {
    float u = v * 144.2695041f;                       // 100 * log2(e)
    float e = __builtin_amdgcn_exp2f(u);
    float y = __builtin_amdgcn_logf(1.f + e) * 0.006931471806f;  // log2->ln, /100
    return v > 0.25f ? v : y;
}

__device__ __forceinline__ unsigned short f2bfu(float v) {
    bf16 h = (bf16)v;
    return *(unsigned short*)&h;
}

// ---------------- weight prep: W = g * v / ||v||_row, cast to bf16, pad ----------------
__global__ void prep_weights(const float* __restrict__ v0, const float* __restrict__ g0,
                             const float* __restrict__ v1, const float* __restrict__ g1,
                             const float* __restrict__ v2, const float* __restrict__ g2,
                             unsigned short* __restrict__ W0, unsigned short* __restrict__ W1,
                             unsigned short* __restrict__ W2) {
    int r = blockIdx.x;
    int lane = threadIdx.x;
    const float* src = nullptr; const float* g = nullptr; unsigned short* dst; int K, Kp, row;
    if (r < 256)      { row = r;       src = v0 + row * 71;  g = g0; dst = W0 + row * 96;  K = 71;  Kp = 96;  }
    else if (r < 512) { row = r - 256; src = v1 + row * 256; g = g1; dst = W1 + row * 256; K = 256; Kp = 256; }
    else              { row = r - 512; if (row < 257) { src = v2 + row * 256; g = g2; }
                        dst = W2 + row * 256; K = 256; Kp = 256; }
    float ss = 0.f;
    if (src) for (int c = lane; c < K; c += 64) { float v = src[c]; ss += v * v; }
    for (int off = 32; off; off >>= 1) ss += __shfl_down(ss, off);
    ss = __shfl(ss, 0);
    float scale = src ? (g[row] / sqrtf(ss)) : 0.f;
    for (int c = lane; c < Kp; c += 64) {
        float v = (src && c < K) ? src[c] * scale : 0.f;
        dst[c] = f2bfu(v);
    }
}

// ---------------- table conversion f32x2 -> packed fp8 e4m3 x2 (u16), scaled 2^13 ----
__global__ void conv_tables(const float2* __restrict__ t, unsigned short* __restrict__ tf8) {
    size_t i = (size_t)blockIdx.x * 256 + threadIdx.x;
    float2 e = t[i];
    int pk = __builtin_amdgcn_cvt_pk_fp8_f32(e.x * FP8_SCALE, e.y * FP8_SCALE, 0, false);
    tf8[i] = (unsigned short)(pk & 0xffff);
}

// ---------------- level-partitioned encode: blockIdx%8 -> XCD slot, 2 levels/slot ----
// fp8 tables: 1MB/level -> 2MB/XCD resident in 4MB L2.
__global__ __launch_bounds__(256, 8)
void encode_levels(const float* __restrict__ x, const unsigned short* __restrict__ tf8,
                   unsigned* __restrict__ featsLM, Levels lv, int npts) {
    const int slot = blockIdx.x & 7, seq = blockIdx.x >> 3;
    const int l = slot + 8 * (seq & 1);
    const int group = seq >> 1;
    const unsigned Ru = lv.R[l], mY = lv.mY[l], mZ = lv.mZ[l];
    const bool dense = lv.df[l] != 0;
    const unsigned short* __restrict__ tl = tf8 + (size_t)l * T_HASH;
    unsigned* __restrict__ fout = featsLM + (size_t)l * npts;
    const float Rf = (float)Ru;
    const int base = group * 1024 + threadIdx.x;
#pragma unroll
    for (int k = 0; k < 4; ++k) {
        const int p = base + k * 256;
        float xr0 = x[p * 3 + 0], xr1 = x[p * 3 + 1], xr2 = x[p * 3 + 2];
        const float cx = fminf(fmaxf(xr0, 0.f), 1.f);
        const float cy = fminf(fmaxf(xr1, 0.f), 1.f);
        const float cz = fminf(fmaxf(xr2, 0.f), 1.f);
        float px = cx * Rf, py = cy * Rf, pz = cz * Rf;
        float fx = floorf(px), fy = floorf(py), fz = floorf(pz);
        float wx = px - fx, wy = py - fy, wz = pz - fz;
        unsigned ix = (unsigned)fx, iy = (unsigned)fy, iz = (unsigned)fz;
        unsigned xc0 = ix, xc1 = umin_(ix + 1u, Ru);
        unsigned y0 = iy * mY, y1 = umin_(iy + 1u, Ru) * mY;
        unsigned z0 = iz * mZ, z1 = umin_(iz + 1u, Ru) * mZ;
        unsigned yzA[4] = { y0 + z0, y1 + z0, y0 + z1, y1 + z1 };
        float w0x = 1.f - wx, w0y = 1.f - wy, w0z = 1.f - wz;
        float wyz[4] = { w0y * w0z, wy * w0z, w0y * wz, wy * wz };
        float a0 = 0.f, a1 = 0.f;
#pragma unroll
        for (int c = 0; c < 8; ++c) {
            const int ox = c & 1, cyz = c >> 1;
            unsigned xc = ox ? xc1 : xc0;
            unsigned gi = dense ? (xc + yzA[cyz])
                                : ((xc ^ yzA[cyz]) & (T_HASH - 1u));
            unsigned u = (unsigned)tl[gi];
            float ex = __builtin_amdgcn_cvt_f32_fp8(u, 0);
            float ey = __builtin_amdgcn_cvt_f32_fp8(u, 1);
            float wc = (ox ? wx : w0x) * wyz[cyz];
            a0 = fmaf(wc, ex, a0);
            a1 = fmaf(wc, ey, a1);
        }
        a0 *= FP8_INV; a1 *= FP8_INV;
        unsigned outw = (unsigned)f2bfu(a0) | ((unsigned)f2bfu(a1) << 16);
        __builtin_nontemporal_store(outw, &fout[p]);
    }
}

// ---------------- fused MLP ----------------
// block = 64 points, 1024 threads (16 waves)  [best measured structure]
// Wave w owns output cols [w*16,w*16+16) for ALL 64 points (4 point-sub-tiles).
// Per K-step: 1 W a-load (depth-2 prefetch, 3-slot rotation) + 4 LDS b-reads + 4 MFMA.
// Col 256 via distributed VALU dot. Flat copy-out (1028 full aligned 64B lines).

#define STG_STRIDE 260   // floats; 1040B row, 16B-aligned

template<int KSTEPS, int ROWLEN>
__device__ __forceinline__ void layer_mid(const char* __restrict__ inbuf,
                                          const unsigned short* __restrict__ W,
                                          const float* __restrict__ bias,
                                          char* __restrict__ outbuf, int tid) {
    const int lane = tid & 63, wave = tid >> 6;
    const int lrow = lane & 15, lk = lane >> 4;
    const unsigned short* __restrict__ wrow = W + (wave * 16 + lrow) * ROWLEN + lk * 8;
    f32x4 acc[4] = {};
    bf16x8 abuf[3];
    abuf[0] = *(const bf16x8*)(wrow);
    if (KSTEPS > 1) abuf[1] = *(const bf16x8*)(wrow + 32);
#pragma unroll
    for (int ks = 0; ks < KSTEPS; ++ks) {
        if (ks + 2 < KSTEPS) abuf[(ks + 2) % 3] = *(const bf16x8*)(wrow + (ks + 2) * 32);
        const int k0 = ks * 32 + lk * 8;
        bf16x8 b[4];
#pragma unroll
        for (int pt = 0; pt < 4; ++pt)
            b[pt] = *(const bf16x8*)(inbuf + swzoff(pt * 16 + lrow, k0 * 2));
#pragma unroll
        for (int pt = 0; pt < 4; ++pt)
            acc[pt] = __builtin_amdgcn_mfma_f32_16x16x32_bf16(abuf[ks % 3], b[pt], acc[pt], 0, 0, 0);
    }
    const int c0 = wave * 16 + lk * 4;
    const float4 bv = *(const float4*)(bias + c0);
#pragma unroll
    for (int pt = 0; pt < 4; ++pt) {
        const int p = pt * 16 + lrow;
        s16x4 o;
        o.x = (short)f2bfu(softplus100f(acc[pt][0] + bv.x));
        o.y = (short)f2bfu(softplus100f(acc[pt][1] + bv.y));
        o.z = (short)f2bfu(softplus100f(acc[pt][2] + bv.z));
        o.w = (short)f2bfu(softplus100f(acc[pt][3] + bv.w));
        *(s16x4*)(outbuf + swzoff(p, c0 * 2)) = o;
    }
}

__device__ __forceinline__ void layer_fin(const char* __restrict__ inbuf,
                                          const unsigned short* __restrict__ W2,
                                          const float* __restrict__ b2,
                                          float* __restrict__ stg,
                                          float* __restrict__ out, int tid, int blk) {
    const int lane = tid & 63, wave = tid >> 6;
    const int lrow = lane & 15, lk = lane >> 4;
    const unsigned short* __restrict__ wrow = W2 + (wave * 16 + lrow) * 256 + lk * 8;
    f32x4 acc[4] = {};
    bf16x8 abuf[3];
    abuf[0] = *(const bf16x8*)(wrow);
    abuf[1] = *(const bf16x8*)(wrow + 32);
#pragma unroll
    for (int ks = 0; ks < 8; ++ks) {
        if (ks + 2 < 8) abuf[(ks + 2) % 3] = *(const bf16x8*)(wrow + (ks + 2) * 32);
        const int k0 = ks * 32 + lk * 8;
        bf16x8 b[4];
#pragma unroll
        for (int pt = 0; pt < 4; ++pt)
            b[pt] = *(const bf16x8*)(inbuf + swzoff(pt * 16 + lrow, k0 * 2));
#pragma unroll
        for (int pt = 0; pt < 4; ++pt)
            acc[pt] = __builtin_amdgcn_mfma_f32_16x16x32_bf16(abuf[ks % 3], b[pt], acc[pt], 0, 0, 0);
    }
    // ---- col 256: distributed VALU dot. p = tid>>4 (64 pts), sub = tid&15, 16 k each ----
    const int p = tid >> 4, sub = tid & 15;
    float part = 0.f;
    {
        const unsigned short* __restrict__ w2r = W2 + 256 * 256 + sub * 16;
        bf16x8 h0 = *(const bf16x8*)(inbuf + swzoff(p, sub * 32));
        bf16x8 h1 = *(const bf16x8*)(inbuf + swzoff(p, sub * 32 + 16));
        bf16x8 w0 = *(const bf16x8*)(w2r);
        bf16x8 w1 = *(const bf16x8*)(w2r + 8);
#pragma unroll
        for (int j = 0; j < 8; ++j) {
            part = fmaf((float)h0[j], (float)w0[j], part);
            part = fmaf((float)h1[j], (float)w1[j], part);
        }
    }
#pragma unroll
    for (int m = 1; m < 16; m <<= 1) part += __shfl_xor(part, m);

    __syncthreads();   // all reads of inbuf done; stg aliases the h-buffers
    const int c0 = wave * 16 + lk * 4;
    const float4 bv = *(const float4*)(b2 + c0);
#pragma unroll
    for (int pt = 0; pt < 4; ++pt) {
        const int pr = pt * 16 + lrow;
        f32x4 v;
        v[0] = acc[pt][0] + bv.x;
        v[1] = acc[pt][1] + bv.y;
        v[2] = acc[pt][2] + bv.z;
        v[3] = acc[pt][3] + bv.w;
        *(f32x4*)(stg + pr * STG_STRIDE + c0) = v;   // 16B-aligned
    }
    if (sub == 0) stg[p * STG_STRIDE + 256] = part + b2[256];
    __syncthreads();
    // ---- flat copy-out: block span = 16448 floats = 1028 full 64B lines, aligned ----
    float* __restrict__ dst = out + (size_t)blk * 16448;
#pragma unroll
    for (int r = 0; r < 4; ++r) {
        const int f0 = (r * 1024 + tid) * 4;
        const unsigned pp = ((unsigned)f0 * 65281u) >> 24;        // f0 / 257
        const int cc = f0 - (int)pp * 257;
        f32x4 v;
#pragma unroll
        for (int u = 0; u < 4; ++u) {
            int c2 = cc + u; unsigned p2 = pp;
            if (c2 >= 257) { c2 -= 257; p2++; }
            v[u] = stg[p2 * STG_STRIDE + c2];
        }
        *(f32x4*)(dst + f0) = v;                 // plain 16B store; L2 assembles lines
    }
    if (tid < 64) {
        const int f0 = 16384 + tid;
        const unsigned pp = ((unsigned)f0 * 65281u) >> 24;
        const int cc = f0 - (int)pp * 257;
        dst[f0] = stg[pp * STG_STRIDE + cc];
    }
}

template<bool SPLIT>
__global__ __launch_bounds__(1024, 8)
void fused_net(const float* __restrict__ x, const float2* __restrict__ tables,
               const unsigned* __restrict__ featsLM,
               const unsigned short* __restrict__ W0, const unsigned short* __restrict__ W1,
               const unsigned short* __restrict__ W2,
               const float* __restrict__ b0, const float* __restrict__ b1, const float* __restrict__ b2,
               float* __restrict__ out, Levels lv, int npts) {
    __shared__ __align__(16) char smem[66560 + 256];   // h-buffers; stg aliases (64*260*4=66560)
    unsigned* sR  = (unsigned*)(smem + 66560);
    unsigned* sMY = sR + 16;
    unsigned* sMZ = sR + 32;
    unsigned* sDF = sR + 48;
    char* buf0 = smem;            // h0, later h2
    char* buf1 = smem + 32768;    // h1
    float* stg = (float*)smem;    // fp32 staging for final output (aliases h-buffers)
    const int tid = threadIdx.x;
    const int blk = blockIdx.x;

    if (!SPLIT) {
        if (tid >= 960) {
            int i = tid - 960;
            if (i < 16)      sR[i]  = lv.R[i];
            else if (i < 32) sMY[i - 16] = lv.mY[i - 16];
            else if (i < 48) sMZ[i - 32] = lv.mZ[i - 32];
            else             sDF[i - 48] = lv.df[i - 48];
        }
        __syncthreads();
    }

    const int p = tid >> 4, sub = tid & 15;
    const float xr0 = x[(size_t)blk * 192 + p * 3 + 0];
    const float xr1 = x[(size_t)blk * 192 + p * 3 + 1];
    const float xr2 = x[(size_t)blk * 192 + p * 3 + 2];

    if (SPLIT) {
        // coalesced feats load: item i = tid -> level l = tid>>6, point pt = tid&63
        // wave reads 64 consecutive u32 of one level = 256B contiguous.
        const int l = tid >> 6, pt = tid & 63;
        unsigned u = featsLM[(size_t)l * npts + blk * 64 + pt];
        stw(buf0, pt, 39 + 2 * l, (unsigned short)(u & 0xffffu));
        stw(buf0, pt, 40 + 2 * l, (unsigned short)(u >> 16));
    }

    // ---- positional embedding: 3 cols per sub-thread (subs 0..12) ----
    if (sub < 13) {
        int c0 = sub * 3;
#pragma unroll
        for (int u = 0; u < 3; ++u) {
            int c = c0 + u;
            if (c >= 39) break;
            float v;
            if (c < 3) v = (c == 0) ? xr0 : (c == 1 ? xr1 : xr2);
            else {
                int q = c - 3, j = q / 6, k = q - j * 6;
                int axis = (k < 3) ? k : k - 3;
                float xv = axis == 0 ? xr0 : (axis == 1 ? xr1 : xr2);
                float fx = (float)(1 << j) * xv;
                v = (k < 3) ? __sinf(fx) : __cosf(fx);
            }
            stb(buf0, p, c, v);
        }
    }
    for (int c = 71 + sub; c < 96; c += 16) stb(buf0, p, c, 0.f);

    if (!SPLIT) {
        // fallback: inline hash gather (1 level per sub-thread), fp32 tables
        const int l = sub;
        const float cx = fminf(fmaxf(xr0, 0.f), 1.f);
        const float cy = fminf(fmaxf(xr1, 0.f), 1.f);
        const float cz = fminf(fmaxf(xr2, 0.f), 1.f);
        const unsigned Ru = sR[l], mY = sMY[l], mZ = sMZ[l];
        const bool dense = sDF[l] != 0;
        const unsigned lofs = (unsigned)l << 19;
        const float Rf = (float)Ru;
        float px = cx * Rf, py = cy * Rf, pz = cz * Rf;
        float fx = floorf(px), fy = floorf(py), fz = floorf(pz);
        float wx = px - fx, wy = py - fy, wz = pz - fz;
        unsigned ix = (unsigned)fx, iy = (unsigned)fy, iz = (unsigned)fz;
        unsigned xc0 = ix, xc1 = umin_(ix + 1u, Ru);
        unsigned y0 = iy * mY, y1 = umin_(iy + 1u, Ru) * mY;
        unsigned z0 = iz * mZ, z1 = umin_(iz + 1u, Ru) * mZ;
        unsigned yzA[4] = { y0 + z0 + lofs, y1 + z0 + lofs, y0 + z1 + lofs, y1 + z1 + lofs };
        unsigned yzX[4] = { y0 ^ z0, y1 ^ z0, y0 ^ z1, y1 ^ z1 };
        float w0x = 1.f - wx, w0y = 1.f - wy, w0z = 1.f - wz;
        float wyz[4] = { w0y * w0z, wy * w0z, w0y * wz, wy * wz };
        float a0 = 0.f, a1 = 0.f;
#pragma unroll
        for (int c = 0; c < 8; ++c) {
            const int ox = c & 1, cyz = c >> 1;
            unsigned xc = ox ? xc1 : xc0;
            unsigned fd = xc + yzA[cyz];
            unsigned fh = ((xc ^ yzX[cyz]) & (T_HASH - 1u)) + lofs;
            unsigned gi = dense ? fd : fh;
            float2 e2 = tables[gi];
            float wc = (ox ? wx : w0x) * wyz[cyz];
            a0 = fmaf(wc, e2.x, a0);
            a1 = fmaf(wc, e2.y, a1);
        }
        stb(buf0, p, 39 + 2 * l, a0);
        stb(buf0, p, 40 + 2 * l, a1);
    }
    __syncthreads();

    layer_mid<3, 96>(buf0, W0, b0, buf1, tid);    // 71(->96) -> 256
    __syncthreads();
    layer_mid<8, 256>(buf1, W1, b1, buf0, tid);   // 256 -> 256
    __syncthreads();
    layer_fin(buf0, W2, b2, stg, out, tid, blk);  // 256 -> 257, flat coalesced out
}

extern "C" void kernel_launch(void* const* d_in, const int* in_sizes, int n_in,
                              void* d_out, int out_size, void* d_ws, size_t ws_size,
                              hipStream_t stream) {
    const float*  x      = (const float*)d_in[0];
    const float2* tables = (const float2*)d_in[1];
    const float*  v0 = (const float*)d_in[2];
    const float*  g0 = (const float*)d_in[3];
    const float*  b0 = (const float*)d_in[4];
    const float*  v1 = (const float*)d_in[5];
    const float*  g1 = (const float*)d_in[6];
    const float*  b1 = (const float*)d_in[7];
    const float*  v2 = (const float*)d_in[8];
    const float*  g2 = (const float*)d_in[9];
    const float*  b2 = (const float*)d_in[10];

    unsigned short* W0 = (unsigned short*)d_ws;          // [256][96]
    unsigned short* W1 = W0 + 256 * 96;                  // [256][256]
    unsigned short* W2 = W1 + 256 * 256;                 // [272][256]
    size_t ofs_tf8   = 319488;                           // fp8 tables: 16 levels x 512K x 2B = 16MB
    size_t ofs_feats = ofs_tf8 + (size_t)16 * T_HASH * 2;
    size_t need      = ofs_feats + (size_t)16 * T_HASH * 4;
    unsigned short* tf8 = (unsigned short*)((char*)d_ws + ofs_tf8);
    unsigned* featsLM   = (unsigned*)((char*)d_ws + ofs_feats);
    bool use_split = ws_size >= need;

    Levels lv;
    double SCALE = pow(2.0, log2(2048.0 / 16.0) / 15.0);
    for (int l = 0; l < 16; ++l) {
        double r = 16.0 * pow(SCALE, (double)l);
        unsigned R = (unsigned)ceil(r);
        lv.R[l] = R;
        unsigned long long s = (unsigned long long)R + 1;
        int dense = (s * s * s <= (unsigned long long)T_HASH) ? 1 : 0;
        lv.df[l] = dense;
        lv.mY[l] = dense ? (R + 1u) : PRIME1;
        lv.mZ[l] = dense ? (R + 1u) * (R + 1u) : PRIME2;
    }

    prep_weights<<<784, 64, 0, stream>>>(v0, g0, v1, g1, v2, g2, W0, W1, W2);

    int n = in_sizes[0] / 3;          // 524288
    int nblk = n / 64;                // 8192

    if (use_split) {
        conv_tables<<<16 * T_HASH / 256, 256, 0, stream>>>(tables, tf8);
        encode_levels<<<8 * (n / 1024) * 2, 256, 0, stream>>>(x, tf8, featsLM, lv, n);
        fused_net<true><<<nblk, 1024, 0, stream>>>(x, tables, featsLM, W0, W1, W2,
                                                   b0, b1, b2, (float*)d_out, lv, n);
    } else {
        fused_net<false><<<nblk, 1024, 0, stream>>>(x, tables, nullptr, W0, W1, W2,
                                                    b0, b1, b2, (float*)d_out, lv, n);
    }
}